// Round 4
// baseline (4421.210 us; speedup 1.0000x reference)
//
#include <hip/hip_runtime.h>
#include <cstdint>
#include <cstddef>

#define L_NUM 8
#define D_DIM 1024
#define H_NUM 16
#define C_DIM 64
#define M_DIM 4096
#define V_DIM 64
#define B_SZ 4
#define T_SZ 2048
#define N_TOK (B_SZ * T_SZ)
#define TMAXP 2048
#define QKV_LD (3 * D_DIM)

typedef __bf16 bf16;
typedef bf16 bf16x4 __attribute__((ext_vector_type(4)));
typedef bf16 bf16x8 __attribute__((ext_vector_type(8)));
typedef float f32x4v __attribute__((ext_vector_type(4)));

// async global->LDS, 16B per lane. LDS dest = wave-uniform base + lane*16.
__device__ __forceinline__ void async16(const bf16* g, bf16* l) {
    __builtin_amdgcn_global_load_lds(
        (const __attribute__((address_space(1))) void*)g,
        (__attribute__((address_space(3))) void*)l, 16, 0, 0);
}

// ---------------------------------------------------------------- convert f32 -> bf16
__global__ __launch_bounds__(256) void convert_kernel(const float* __restrict__ src,
                                                      bf16* __restrict__ dst, int n) {
    int i = (blockIdx.x * 256 + threadIdx.x) * 4;
    if (i >= n) return;
    const float4 v = *(const float4*)(src + i);
    bf16x4 o;
    o[0] = (bf16)v.x; o[1] = (bf16)v.y; o[2] = (bf16)v.z; o[3] = (bf16)v.w;
    *(bf16x4*)(dst + i) = o;
}

// ---------------------------------------------------------------- wpos [D][TMAX] -> posT [TMAX][D]
__global__ __launch_bounds__(256) void transpose_pos(const float* __restrict__ in,
                                                     float* __restrict__ out) {
    __shared__ float tile[32][33];
    const int t0 = blockIdx.x * 32, d0 = blockIdx.y * 32;
    const int tx = threadIdx.x & 31, ty = threadIdx.x >> 5;
#pragma unroll
    for (int j = 0; j < 32; j += 8)
        tile[ty + j][tx] = in[(size_t)(d0 + ty + j) * TMAXP + t0 + tx];
    __syncthreads();
#pragma unroll
    for (int j = 0; j < 32; j += 8)
        out[(size_t)(t0 + ty + j) * D_DIM + d0 + tx] = tile[tx][ty + j];
}

// ---------------------------------------------------------------- layernorm (fp32 in, bf16 out)
__global__ __launch_bounds__(256) void ln_kernel(const float* __restrict__ x,
                                                 const float* __restrict__ g,
                                                 const float* __restrict__ b,
                                                 bf16* __restrict__ y) {
    const int n = blockIdx.x, tid = threadIdx.x;
    const float4 v = ((const float4*)(x + (size_t)n * D_DIM))[tid];
    float s = v.x + v.y + v.z + v.w;
    float q = v.x * v.x + v.y * v.y + v.z * v.z + v.w * v.w;
#pragma unroll
    for (int off = 32; off > 0; off >>= 1) {
        s += __shfl_xor(s, off);
        q += __shfl_xor(q, off);
    }
    __shared__ float s1[4], s2[4];
    if ((tid & 63) == 0) { s1[tid >> 6] = s; s2[tid >> 6] = q; }
    __syncthreads();
    s = s1[0] + s1[1] + s1[2] + s1[3];
    q = s2[0] + s2[1] + s2[2] + s2[3];
    const float mu = s * (1.f / D_DIM);
    const float var = q * (1.f / D_DIM) - mu * mu;
    const float rs = rsqrtf(var + 1e-5f);
    const float4 gg = ((const float4*)g)[tid];
    const float4 bb = ((const float4*)b)[tid];
    bf16x4 o;
    o[0] = (bf16)((v.x - mu) * rs * gg.x + bb.x);
    o[1] = (bf16)((v.y - mu) * rs * gg.y + bb.y);
    o[2] = (bf16)((v.z - mu) * rs * gg.z + bb.z);
    o[3] = (bf16)((v.w - mu) * rs * gg.w + bb.w);
    ((bf16x4*)(y + (size_t)n * D_DIM))[tid] = o;
}

// ---------------------------------------------------------------- GEMM: C[M,N] = A[M,K] @ W[N,K]^T
// 128x128 tile, BK=64, global_load_lds width-16 staging with XOR-8 chunk swizzle.
// MODE 0: store bf16. MODE 1: +bias, relu, bf16. MODE 2: +bias+add1+add2, f32.
// MODE 3: +posT[(row%T)*Nc+col] (add1=posT), f32.
template <int MODE>
__global__ __launch_bounds__(256) void gemm_bt(const bf16* __restrict__ A,
                                               const bf16* __restrict__ W,
                                               const float* __restrict__ bias,
                                               const float* add1, const float* add2,
                                               float* outF, bf16* outB, int K, int Nc) {
    __shared__ __align__(16) bf16 As[128][64];
    __shared__ __align__(16) bf16 Bs[128][64];
    const int tid = threadIdx.x;
    const int lane = tid & 63, w = tid >> 6;
    const int wm = w >> 1, wn = w & 1;
    const int l15 = lane & 15, quad = lane >> 4;
    const size_t rowbase = (size_t)blockIdx.y * 128;
    const size_t colbase = (size_t)blockIdx.x * 128;
    f32x4v acc[4][4] = {};
    const int rsub = lane >> 3;
    const int schunk = lane & 7;
    const int gchunk = schunk ^ rsub;
    const bf16* Ag = A + (rowbase + w * 32 + rsub) * (size_t)K + gchunk * 8;
    const bf16* Wg = W + (colbase + w * 32 + rsub) * (size_t)K + gchunk * 8;
    bf16* Asl = &As[w * 32][0];
    bf16* Bsl = &Bs[w * 32][0];
    const int swz = l15 & 7;
    for (int k0 = 0; k0 < K; k0 += 64) {
        __syncthreads();
#pragma unroll
        for (int i = 0; i < 4; ++i) {
            async16(Ag + k0 + (size_t)(i * 8) * K, Asl + i * 512);
            async16(Wg + k0 + (size_t)(i * 8) * K, Bsl + i * 512);
        }
        __syncthreads();
#pragma unroll
        for (int kk = 0; kk < 2; ++kk) {
            const int q = kk * 4 + quad;
            bf16x8 af[4], bv[4];
#pragma unroll
            for (int f = 0; f < 4; ++f) {
                af[f] = *(const bf16x8*)&As[wm * 64 + f * 16 + l15][(q ^ swz) * 8];
                bv[f] = *(const bf16x8*)&Bs[wn * 64 + f * 16 + l15][(q ^ swz) * 8];
            }
#pragma unroll
            for (int fm = 0; fm < 4; ++fm)
#pragma unroll
                for (int fn = 0; fn < 4; ++fn)
                    acc[fm][fn] = __builtin_amdgcn_mfma_f32_16x16x32_bf16(af[fm], bv[fn], acc[fm][fn], 0, 0, 0);
        }
    }
    float bcol[4];
    if (MODE == 1 || MODE == 2) {
#pragma unroll
        for (int fn = 0; fn < 4; ++fn) bcol[fn] = bias[colbase + wn * 64 + fn * 16 + l15];
    }
#pragma unroll
    for (int fm = 0; fm < 4; ++fm) {
#pragma unroll
        for (int r = 0; r < 4; ++r) {
            const size_t row = rowbase + wm * 64 + fm * 16 + quad * 4 + r;
            const size_t base = row * (size_t)Nc + colbase + wn * 64 + l15;
#pragma unroll
            for (int fn = 0; fn < 4; ++fn) {
                float v = acc[fm][fn][r];
                const size_t idx = base + fn * 16;
                if (MODE == 0) {
                    outB[idx] = (bf16)v;
                } else if (MODE == 1) {
                    v += bcol[fn];
                    outB[idx] = (bf16)fmaxf(v, 0.f);
                } else if (MODE == 2) {
                    v += bcol[fn] + add1[idx] + add2[idx];
                    outF[idx] = v;
                } else {
                    const size_t t = row & (T_SZ - 1);
                    const size_t col = colbase + wn * 64 + fn * 16 + l15;
                    v += add1[t * (size_t)Nc + col];
                    outF[idx] = v;
                }
            }
        }
    }
}

// ---------------------------------------------------------------- GEMM 256x256, BK=64, 8 waves,
// double-buffered LDS (128 KiB), prefetch issued BEFORE compute so the barrier's vmcnt(0) drain
// lands after the 64-MFMA cluster. One __syncthreads per K-step. Same verified XOR-chunk swizzle
// (pre-swizzled global source, linear LDS dest, swizzled ds_read) as gemm_bt.
// MODE 1 only in use: +bias, relu, bf16 out.
template <int MODE>
__global__ __launch_bounds__(512, 2) void gemm256_bt(const bf16* __restrict__ A,
                                                     const bf16* __restrict__ W,
                                                     const float* __restrict__ bias,
                                                     float* outF, bf16* outB, int K, int Nc) {
    __shared__ __align__(16) bf16 As[2][256][64];
    __shared__ __align__(16) bf16 Bs[2][256][64];
    const int tid = threadIdx.x;
    const int lane = tid & 63, w = tid >> 6;       // 8 waves
    const int wm = w >> 2, wn = w & 3;             // 2M x 4N wave grid: per-wave C = 128x64
    const int l15 = lane & 15, quad = lane >> 4;
    const size_t rowbase = (size_t)blockIdx.y * 256;
    const size_t colbase = (size_t)blockIdx.x * 256;
    f32x4v acc[8][4] = {};
    const int rsub = lane >> 3;
    const int schunk = lane & 7;
    const int gchunk = schunk ^ rsub;              // pre-swizzled global chunk
    const bf16* Ag = A + (rowbase + w * 32 + rsub) * (size_t)K + gchunk * 8;
    const bf16* Wg = W + (colbase + w * 32 + rsub) * (size_t)K + gchunk * 8;
    const int swz = l15 & 7;
    const int nk = K / 64;
    // prologue: stage K-tile 0 into buffer 0 (each wave stages 32 rows of A and 32 of B)
#pragma unroll
    for (int i = 0; i < 4; ++i) {
        async16(Ag + (size_t)(i * 8) * K, &As[0][w * 32][0] + i * 512);
        async16(Wg + (size_t)(i * 8) * K, &Bs[0][w * 32][0] + i * 512);
    }
    __syncthreads();  // vmcnt(0) drain: tile 0 resident
    for (int t = 0; t < nk; ++t) {
        const int cur = t & 1;
        if (t + 1 < nk) {  // issue next tile's 8 loads BEFORE compute — full-phase overlap
            const size_t ko = (size_t)(t + 1) * 64;
#pragma unroll
            for (int i = 0; i < 4; ++i) {
                async16(Ag + ko + (size_t)(i * 8) * K, &As[cur ^ 1][w * 32][0] + i * 512);
                async16(Wg + ko + (size_t)(i * 8) * K, &Bs[cur ^ 1][w * 32][0] + i * 512);
            }
        }
        __builtin_amdgcn_s_setprio(1);
#pragma unroll
        for (int kk = 0; kk < 2; ++kk) {
            const int q = kk * 4 + quad;
            bf16x8 af[8], bv[4];
#pragma unroll
            for (int f = 0; f < 8; ++f)
                af[f] = *(const bf16x8*)&As[cur][wm * 128 + f * 16 + l15][(q ^ swz) * 8];
#pragma unroll
            for (int f = 0; f < 4; ++f)
                bv[f] = *(const bf16x8*)&Bs[cur][wn * 64 + f * 16 + l15][(q ^ swz) * 8];
#pragma unroll
            for (int fm = 0; fm < 8; ++fm)
#pragma unroll
                for (int fn = 0; fn < 4; ++fn)
                    acc[fm][fn] = __builtin_amdgcn_mfma_f32_16x16x32_bf16(af[fm], bv[fn], acc[fm][fn], 0, 0, 0);
        }
        __builtin_amdgcn_s_setprio(0);
        // single barrier per K-step: implicit vmcnt(0) waits the prefetch (covered by the MFMAs
        // above); implicit lgkmcnt(0) + barrier makes buffer `cur` safe to overwrite next iter.
        __syncthreads();
    }
    float bcol[4];
    if (MODE == 1) {
#pragma unroll
        for (int fn = 0; fn < 4; ++fn) bcol[fn] = bias[colbase + wn * 64 + fn * 16 + l15];
    }
#pragma unroll
    for (int fm = 0; fm < 8; ++fm) {
#pragma unroll
        for (int r = 0; r < 4; ++r) {
            const size_t row = rowbase + wm * 128 + fm * 16 + quad * 4 + r;
            const size_t base = row * (size_t)Nc + colbase + wn * 64 + l15;
#pragma unroll
            for (int fn = 0; fn < 4; ++fn) {
                float v = acc[fm][fn][r];
                const size_t idx = base + fn * 16;
                if (MODE == 1) {
                    v += bcol[fn];
                    outB[idx] = (bf16)fmaxf(v, 0.f);
                } else {
                    outF[idx] = v;
                }
            }
        }
    }
}

// ---------------------------------------------------------------- MFMA flash attention (S^T formulation)
// grid (T/128, H, B), 4 waves; wave w owns q rows [w*32, w*32+32). qt reversed for load balance.
// S^T = mfma(A=K, B=Q): lane holds S^T[s=quad*4+r][q=l15] -> 4 consecutive s per lane:
// softmax reduces via shfl_xor(16,32) only; P stored as b64; alpha/l realigned via __shfl.
// K/V register-prefetched one tile ahead; all LDS layouts bank-uniform.
__global__ __launch_bounds__(256) void attn_kernel(const bf16* __restrict__ qkv,
                                                   const float* __restrict__ x,
                                                   float* __restrict__ h) {
    const int qt = (int)gridDim.x - 1 - (int)blockIdx.x;  // longest strips first
    const int hh = blockIdx.y, b = blockIdx.z;
    const int tid = threadIdx.x;
    const int lane = tid & 63, w = tid >> 6;
    const int quad = lane >> 4, l15 = lane & 15;

    __shared__ __align__(16) bf16 Ks[64][64];     // XOR-swizzled chunks
    __shared__ __align__(16) bf16 Vt[64][72];     // [ch][s]
    __shared__ __align__(16) bf16 Ps[4][16][80];  // per-wave P: [q][s], pad 80

    // Q fragments: B-frag [n=q=l15][k=ch]
    bf16x8 Qf[2][2];
#pragma unroll
    for (int qsub = 0; qsub < 2; ++qsub)
#pragma unroll
        for (int kc = 0; kc < 2; ++kc)
            Qf[qsub][kc] = *(const bf16x8*)(qkv +
                ((size_t)(b * T_SZ + qt * 128 + w * 32 + qsub * 16 + l15)) * QKV_LD +
                hh * 192 + kc * 32 + quad * 8);

    f32x4v accO[2][4] = {};
    float m_[2] = {-1e30f, -1e30f}, l_[2] = {0.f, 0.f};

    const int qwave = qt * 128 + w * 32;
    const int nst = 2 * qt + 2;
    constexpr float SC = 0.125f * 1.44269504f;  // scale * log2(e)

    // staging geometry
    const int krow = lane >> 3;          // 0..7 within 8-row group
    const int kchunk = lane & 7;         // global 16B chunk
    const int kswz = kchunk ^ krow;      // LDS chunk (XOR swizzle)
    const bf16* kptr = qkv + ((size_t)(b * T_SZ) + w * 16 + krow) * QKV_LD +
                       hh * 192 + 64 + kchunk * 8;
    const bf16* vptr0 = qkv + ((size_t)(b * T_SZ) + w * 8) * QKV_LD + hh * 192 + 128 + lane;
    const bf16* vptr1 = qkv + ((size_t)(b * T_SZ) + (w + 4) * 8) * QKV_LD + hh * 192 + 128 + lane;

    // prologue prefetch (tile 0)
    uint4 kr0 = *(const uint4*)(kptr);
    uint4 kr1 = *(const uint4*)(kptr + (size_t)8 * QKV_LD);
    bf16x8 vv0, vv1;
#pragma unroll
    for (int j = 0; j < 8; ++j) { vv0[j] = vptr0[(size_t)j * QKV_LD]; vv1[j] = vptr1[(size_t)j * QKV_LD]; }
    kptr += (size_t)64 * QKV_LD; vptr0 += (size_t)64 * QKV_LD; vptr1 += (size_t)64 * QKV_LD;

    for (int st = 0; st < nst; ++st) {
        const int sbase = st * 64;
        __syncthreads();  // protect Ks/Vt against previous tile's readers
        *(uint4*)&Ks[w * 16 + krow][kswz * 8] = kr0;
        *(uint4*)&Ks[w * 16 + 8 + krow][kswz * 8] = kr1;
        *(bf16x8*)&Vt[lane][w * 8] = vv0;
        *(bf16x8*)&Vt[lane][(w + 4) * 8] = vv1;
        __syncthreads();
        if (st + 1 < nst) {  // prefetch next tile (overlaps compute below)
            kr0 = *(const uint4*)(kptr);
            kr1 = *(const uint4*)(kptr + (size_t)8 * QKV_LD);
#pragma unroll
            for (int j = 0; j < 8; ++j) { vv0[j] = vptr0[(size_t)j * QKV_LD]; vv1[j] = vptr1[(size_t)j * QKV_LD]; }
            kptr += (size_t)64 * QKV_LD; vptr0 += (size_t)64 * QKV_LD; vptr1 += (size_t)64 * QKV_LD;
        }
        if (sbase <= qwave + 31) {
#pragma unroll
            for (int qsub = 0; qsub < 2; ++qsub) {
                const int qb = qwave + qsub * 16;  // q = qb + l15
                // --- S^T = K Q^T ---
                f32x4v St[4] = {};
                __builtin_amdgcn_s_setprio(1);
#pragma unroll
                for (int ssub = 0; ssub < 4; ++ssub)
#pragma unroll
                    for (int kc = 0; kc < 2; ++kc) {
                        bf16x8 Kf = *(const bf16x8*)&Ks[ssub * 16 + l15][((kc * 4 + quad) ^ (l15 & 7)) * 8];
                        St[ssub] = __builtin_amdgcn_mfma_f32_16x16x32_bf16(Kf, Qf[qsub][kc], St[ssub], 0, 0, 0);
                    }
                __builtin_amdgcn_s_setprio(0);
                // --- scale to log2 domain + causal mask ---
                float sv[4][4];
#pragma unroll
                for (int ssub = 0; ssub < 4; ++ssub)
#pragma unroll
                    for (int r = 0; r < 4; ++r) sv[ssub][r] = St[ssub][r] * SC;
                if (sbase + 63 > qb) {
#pragma unroll
                    for (int ssub = 0; ssub < 4; ++ssub) {
#pragma unroll
                        for (int r = 0; r < 4; ++r) {
                            const int s = sbase + ssub * 16 + quad * 4 + r;
                            if (s > qb + l15) sv[ssub][r] = -1e38f;
                        }
                    }
                }
                // --- online softmax per q (=l15), cross-quad via shfl 16/32 ---
                float mx = sv[0][0];
#pragma unroll
                for (int ssub = 0; ssub < 4; ++ssub)
#pragma unroll
                    for (int r = 0; r < 4; ++r) mx = fmaxf(mx, sv[ssub][r]);
                mx = fmaxf(mx, __shfl_xor(mx, 16));
                mx = fmaxf(mx, __shfl_xor(mx, 32));
                const float mold = m_[qsub];
                const float mnew = fmaxf(mold, mx);
                const float al = exp2f(mold - mnew);
                float rs = 0.f;
                float p[4][4];
#pragma unroll
                for (int ssub = 0; ssub < 4; ++ssub)
#pragma unroll
                    for (int r = 0; r < 4; ++r) {
                        p[ssub][r] = exp2f(sv[ssub][r] - mnew);
                        rs += p[ssub][r];
                    }
                rs += __shfl_xor(rs, 16);
                rs += __shfl_xor(rs, 32);
                l_[qsub] = l_[qsub] * al + rs;
                m_[qsub] = mnew;
                // --- store P (b64, bank-uniform) ---
#pragma unroll
                for (int ssub = 0; ssub < 4; ++ssub) {
                    bf16x4 pk;
#pragma unroll
                    for (int r = 0; r < 4; ++r) pk[r] = (bf16)p[ssub][r];
                    *(bf16x4*)&Ps[w][l15][ssub * 16 + quad * 4] = pk;
                }
                // --- realign alpha to PV C-layout rows & rescale O ---
                float alr[4];
#pragma unroll
                for (int r = 0; r < 4; ++r) alr[r] = __shfl(al, quad * 4 + r);
#pragma unroll
                for (int nsub = 0; nsub < 4; ++nsub)
#pragma unroll
                    for (int r = 0; r < 4; ++r) accO[qsub][nsub][r] *= alr[r];
                // --- O += P V ---
                __builtin_amdgcn_s_setprio(1);
#pragma unroll
                for (int kc2 = 0; kc2 < 2; ++kc2) {
                    bf16x8 Pf = *(const bf16x8*)&Ps[w][l15][kc2 * 32 + quad * 8];
#pragma unroll
                    for (int nsub = 0; nsub < 4; ++nsub) {
                        bf16x8 Vf = *(const bf16x8*)&Vt[nsub * 16 + l15][kc2 * 32 + quad * 8];
                        accO[qsub][nsub] =
                            __builtin_amdgcn_mfma_f32_16x16x32_bf16(Pf, Vf, accO[qsub][nsub], 0, 0, 0);
                    }
                }
                __builtin_amdgcn_s_setprio(0);
            }
        }
    }
    // --- epilogue: h = x + O / l ---
#pragma unroll
    for (int qsub = 0; qsub < 2; ++qsub) {
        const float linv = 1.f / l_[qsub];
        float invr[4];
#pragma unroll
        for (int r = 0; r < 4; ++r) invr[r] = __shfl(linv, quad * 4 + r);
#pragma unroll
        for (int r = 0; r < 4; ++r) {
            const size_t row = (size_t)(b * T_SZ + qt * 128 + w * 32 + qsub * 16 + quad * 4 + r);
            const size_t base = row * D_DIM + (size_t)hh * 64 + l15;
#pragma unroll
            for (int nsub = 0; nsub < 4; ++nsub) {
                const size_t idx = base + nsub * 16;
                h[idx] = x[idx] + accO[qsub][nsub][r] * invr[r];
            }
        }
    }
}

// ---------------------------------------------------------------- unembed MFMA: out[M,64] = A[M,1024] @ W[64,1024]^T + bun
__global__ __launch_bounds__(256) void unembed_kernel(const bf16* __restrict__ A,
                                                      const bf16* __restrict__ W,
                                                      const float* __restrict__ bun,
                                                      float* __restrict__ out) {
    __shared__ __align__(16) bf16 As[128][64];
    __shared__ __align__(16) bf16 Ws[64][64];
    const int tid = threadIdx.x, lane = tid & 63, w = tid >> 6;
    const int l15 = lane & 15, quad = lane >> 4;
    const size_t rowbase = (size_t)blockIdx.x * 128;
    const int rsub = lane >> 3, schunk = lane & 7, gchunk = schunk ^ rsub;
    const bf16* Ag = A + (rowbase + w * 32 + rsub) * (size_t)D_DIM + gchunk * 8;
    const bf16* Wg = W + (w * 16 + rsub) * (size_t)D_DIM + gchunk * 8;
    bf16* Asl = &As[w * 32][0];
    bf16* Wsl = &Ws[w * 16][0];
    const int swz = l15 & 7;
    f32x4v acc[2][4] = {};
    for (int k0 = 0; k0 < D_DIM; k0 += 64) {
        __syncthreads();
#pragma unroll
        for (int i = 0; i < 4; ++i)
            async16(Ag + k0 + (size_t)(i * 8) * D_DIM, Asl + i * 512);
#pragma unroll
        for (int i = 0; i < 2; ++i)
            async16(Wg + k0 + (size_t)(i * 8) * D_DIM, Wsl + i * 512);
        __syncthreads();
#pragma unroll
        for (int kk = 0; kk < 2; ++kk) {
            const int q = kk * 4 + quad;
            bf16x8 af[2], bv[4];
#pragma unroll
            for (int f = 0; f < 2; ++f) af[f] = *(const bf16x8*)&As[w * 32 + f * 16 + l15][(q ^ swz) * 8];
#pragma unroll
            for (int f = 0; f < 4; ++f) bv[f] = *(const bf16x8*)&Ws[f * 16 + l15][(q ^ swz) * 8];
#pragma unroll
            for (int fm = 0; fm < 2; ++fm)
#pragma unroll
                for (int fn = 0; fn < 4; ++fn)
                    acc[fm][fn] = __builtin_amdgcn_mfma_f32_16x16x32_bf16(af[fm], bv[fn], acc[fm][fn], 0, 0, 0);
        }
    }
#pragma unroll
    for (int fm = 0; fm < 2; ++fm)
#pragma unroll
        for (int r = 0; r < 4; ++r) {
            const size_t row = rowbase + w * 32 + fm * 16 + quad * 4 + r;
#pragma unroll
            for (int fn = 0; fn < 4; ++fn) {
                const int col = fn * 16 + l15;
                out[row * V_DIM + col] = acc[fm][fn][r] + bun[col];
            }
        }
}

// ---------------------------------------------------------------- host
extern "C" void kernel_launch(void* const* d_in, const int* in_sizes, int n_in,
                              void* d_out, int out_size, void* d_ws, size_t ws_size,
                              hipStream_t stream) {
    (void)in_sizes; (void)n_in; (void)out_size;
    const float* toks = (const float*)d_in[0];
    const float* wtok = (const float*)d_in[1];
    const float* wpos = (const float*)d_in[2];
    const float* wqkv = (const float*)d_in[3];
    const float* g1   = (const float*)d_in[4];
    const float* be1  = (const float*)d_in[5];
    const float* w1   = (const float*)d_in[6];
    const float* bm1  = (const float*)d_in[7];
    const float* w2   = (const float*)d_in[8];
    const float* bm2  = (const float*)d_in[9];
    const float* g2   = (const float*)d_in[10];
    const float* be2  = (const float*)d_in[11];
    const float* gf   = (const float*)d_in[12];
    const float* bfp  = (const float*)d_in[13];
    const float* wun  = (const float*)d_in[14];
    const float* bun  = (const float*)d_in[15];
    float* out = (float*)d_out;

    char* ws = (char*)d_ws;
    size_t off = 0;
    auto take = [&](size_t n) { char* p = ws + off; off += (n + 255) & ~(size_t)255; return p; };
    float* xf   = (float*)take((size_t)N_TOK * D_DIM * 4);
    float* hf   = (float*)take((size_t)N_TOK * D_DIM * 4);
    bf16* lnb   = (bf16*)take((size_t)N_TOK * D_DIM * 2);
    bf16* qkvb  = (bf16*)take((size_t)N_TOK * 3 * D_DIM * 2);
    bf16* a1b   = (bf16*)take((size_t)N_TOK * M_DIM * 2);
    bf16* toksb = (bf16*)take((size_t)N_TOK * V_DIM * 2);
    bf16* wtokb = (bf16*)take((size_t)D_DIM * V_DIM * 2);
    bf16* wunb  = (bf16*)take((size_t)V_DIM * D_DIM * 2);
    float* posT = (float*)take((size_t)TMAXP * D_DIM * 4);

    const size_t perL_q = (size_t)3 * D_DIM * D_DIM;   // elems
    const size_t perL_1 = (size_t)M_DIM * D_DIM;
    const size_t perL_2 = (size_t)D_DIM * M_DIM;
    const size_t all_bytes = (size_t)L_NUM * (perL_q + perL_1 + perL_2) * 2 + 4096;
    const bool pre = (ws_size > off) && (ws_size - off >= all_bytes);

    bf16 *wqb, *w1b, *w2b;
    if (pre) {
        wqb = (bf16*)take((size_t)L_NUM * perL_q * 2);
        w1b = (bf16*)take((size_t)L_NUM * perL_1 * 2);
        w2b = (bf16*)take((size_t)L_NUM * perL_2 * 2);
    } else {
        wqb = (bf16*)take(perL_q * 2);
        w1b = (bf16*)take(perL_1 * 2);
        w2b = (bf16*)take(perL_2 * 2);
    }

    convert_kernel<<<(N_TOK * V_DIM) / 1024, 256, 0, stream>>>(toks, toksb, N_TOK * V_DIM);
    convert_kernel<<<(D_DIM * V_DIM) / 1024, 256, 0, stream>>>(wtok, wtokb, D_DIM * V_DIM);
    transpose_pos<<<dim3(TMAXP / 32, D_DIM / 32), 256, 0, stream>>>(wpos, posT);
    gemm_bt<3><<<dim3(D_DIM / 128, N_TOK / 128), 256, 0, stream>>>(
        toksb, wtokb, nullptr, posT, nullptr, xf, nullptr, V_DIM, D_DIM);

    if (pre) {  // hoist all weight converts out of the layer loop (3 launches instead of 24)
        convert_kernel<<<(int)((L_NUM * perL_q) / 1024), 256, 0, stream>>>(
            wqkv, wqb, (int)(L_NUM * perL_q));
        convert_kernel<<<(int)((L_NUM * perL_1) / 1024), 256, 0, stream>>>(
            w1, w1b, (int)(L_NUM * perL_1));
        convert_kernel<<<(int)((L_NUM * perL_2) / 1024), 256, 0, stream>>>(
            w2, w2b, (int)(L_NUM * perL_2));
    }

    for (int l = 0; l < L_NUM; ++l) {
        bf16* wq_l = pre ? wqb + (size_t)l * perL_q : wqb;
        bf16* w1_l = pre ? w1b + (size_t)l * perL_1 : w1b;
        bf16* w2_l = pre ? w2b + (size_t)l * perL_2 : w2b;
        if (!pre)
            convert_kernel<<<(int)(perL_q / 1024), 256, 0, stream>>>(
                wqkv + (size_t)l * perL_q, wq_l, (int)perL_q);
        ln_kernel<<<N_TOK, 256, 0, stream>>>(xf, g1 + l * D_DIM, be1 + l * D_DIM, lnb);
        gemm_bt<0><<<dim3(3 * D_DIM / 128, N_TOK / 128), 256, 0, stream>>>(
            lnb, wq_l, nullptr, nullptr, nullptr, nullptr, qkvb, D_DIM, 3 * D_DIM);
        attn_kernel<<<dim3(T_SZ / 128, H_NUM, B_SZ), 256, 0, stream>>>(qkvb, xf, hf);
        ln_kernel<<<N_TOK, 256, 0, stream>>>(hf, g2 + l * D_DIM, be2 + l * D_DIM, lnb);
        if (!pre)
            convert_kernel<<<(int)(perL_1 / 1024), 256, 0, stream>>>(
                w1 + (size_t)l * perL_1, w1_l, (int)perL_1);
        // MLP1: 256x256 double-buffered GEMM — grid 16x32 = 512 blocks = exactly 2 full
        // rounds of 256 CUs at 1 block/CU (128 KiB LDS).
        gemm256_bt<1><<<dim3(M_DIM / 256, N_TOK / 256), 512, 0, stream>>>(
            lnb, w1_l, bm1 + l * M_DIM, nullptr, a1b, D_DIM, M_DIM);
        if (!pre)
            convert_kernel<<<(int)(perL_2 / 1024), 256, 0, stream>>>(
                w2 + (size_t)l * perL_2, w2_l, (int)perL_2);
        gemm_bt<2><<<dim3(D_DIM / 128, N_TOK / 128), 256, 0, stream>>>(
            a1b, w2_l, bm2 + l * D_DIM, xf, hf, xf, nullptr, M_DIM, D_DIM);
    }
    ln_kernel<<<N_TOK, 256, 0, stream>>>(xf, gf, bfp, lnb);
    convert_kernel<<<(V_DIM * D_DIM) / 1024, 256, 0, stream>>>(wun, wunb, V_DIM * D_DIM);
    unembed_kernel<<<N_TOK / 128, 256, 0, stream>>>(lnb, wunb, bun, out);
}

// Round 8
// 3582.401 us; speedup vs baseline: 1.2341x; 1.2341x over previous
//
#include <hip/hip_runtime.h>
#include <cstdint>
#include <cstddef>

#define L_NUM 8
#define D_DIM 1024
#define H_NUM 16
#define C_DIM 64
#define M_DIM 4096
#define V_DIM 64
#define B_SZ 4
#define T_SZ 2048
#define N_TOK (B_SZ * T_SZ)
#define TMAXP 2048
#define QKV_LD (3 * D_DIM)

typedef __bf16 bf16;
typedef bf16 bf16x4 __attribute__((ext_vector_type(4)));
typedef bf16 bf16x8 __attribute__((ext_vector_type(8)));
typedef float f32x4v __attribute__((ext_vector_type(4)));

// async global->LDS, 16B per lane. LDS dest = wave-uniform base + lane*16.
__device__ __forceinline__ void async16(const bf16* g, bf16* l) {
    __builtin_amdgcn_global_load_lds(
        (const __attribute__((address_space(1))) void*)g,
        (__attribute__((address_space(3))) void*)l, 16, 0, 0);
}

// ---------------------------------------------------------------- convert f32 -> bf16
__global__ __launch_bounds__(256) void convert_kernel(const float* __restrict__ src,
                                                      bf16* __restrict__ dst, int n) {
    int i = (blockIdx.x * 256 + threadIdx.x) * 4;
    if (i >= n) return;
    const float4 v = *(const float4*)(src + i);
    bf16x4 o;
    o[0] = (bf16)v.x; o[1] = (bf16)v.y; o[2] = (bf16)v.z; o[3] = (bf16)v.w;
    *(bf16x4*)(dst + i) = o;
}

// ---------------------------------------------------------------- wpos [D][TMAX] -> posT [TMAX][D]
__global__ __launch_bounds__(256) void transpose_pos(const float* __restrict__ in,
                                                     float* __restrict__ out) {
    __shared__ float tile[32][33];
    const int t0 = blockIdx.x * 32, d0 = blockIdx.y * 32;
    const int tx = threadIdx.x & 31, ty = threadIdx.x >> 5;
#pragma unroll
    for (int j = 0; j < 32; j += 8)
        tile[ty + j][tx] = in[(size_t)(d0 + ty + j) * TMAXP + t0 + tx];
    __syncthreads();
#pragma unroll
    for (int j = 0; j < 32; j += 8)
        out[(size_t)(t0 + ty + j) * D_DIM + d0 + tx] = tile[tx][ty + j];
}

// ---------------------------------------------------------------- layernorm (fp32 in, bf16 out)
__global__ __launch_bounds__(256) void ln_kernel(const float* __restrict__ x,
                                                 const float* __restrict__ g,
                                                 const float* __restrict__ b,
                                                 bf16* __restrict__ y) {
    const int n = blockIdx.x, tid = threadIdx.x;
    const float4 v = ((const float4*)(x + (size_t)n * D_DIM))[tid];
    float s = v.x + v.y + v.z + v.w;
    float q = v.x * v.x + v.y * v.y + v.z * v.z + v.w * v.w;
#pragma unroll
    for (int off = 32; off > 0; off >>= 1) {
        s += __shfl_xor(s, off);
        q += __shfl_xor(q, off);
    }
    __shared__ float s1[4], s2[4];
    if ((tid & 63) == 0) { s1[tid >> 6] = s; s2[tid >> 6] = q; }
    __syncthreads();
    s = s1[0] + s1[1] + s1[2] + s1[3];
    q = s2[0] + s2[1] + s2[2] + s2[3];
    const float mu = s * (1.f / D_DIM);
    const float var = q * (1.f / D_DIM) - mu * mu;
    const float rs = rsqrtf(var + 1e-5f);
    const float4 gg = ((const float4*)g)[tid];
    const float4 bb = ((const float4*)b)[tid];
    bf16x4 o;
    o[0] = (bf16)((v.x - mu) * rs * gg.x + bb.x);
    o[1] = (bf16)((v.y - mu) * rs * gg.y + bb.y);
    o[2] = (bf16)((v.z - mu) * rs * gg.z + bb.z);
    o[3] = (bf16)((v.w - mu) * rs * gg.w + bb.w);
    ((bf16x4*)(y + (size_t)n * D_DIM))[tid] = o;
}

// ---------------------------------------------------------------- GEMM: C[M,N] = A[M,K] @ W[N,K]^T
// 128x128 tile, BK=64, global_load_lds width-16 staging with XOR-8 chunk swizzle.
// MODE 0: store bf16. MODE 1: +bias, relu, bf16. MODE 2: +bias+add1+add2, f32.
// MODE 3: +posT[(row%T)*Nc+col] (add1=posT), f32.
template <int MODE>
__global__ __launch_bounds__(256) void gemm_bt(const bf16* __restrict__ A,
                                               const bf16* __restrict__ W,
                                               const float* __restrict__ bias,
                                               const float* add1, const float* add2,
                                               float* outF, bf16* outB, int K, int Nc) {
    __shared__ __align__(16) bf16 As[128][64];
    __shared__ __align__(16) bf16 Bs[128][64];
    const int tid = threadIdx.x;
    const int lane = tid & 63, w = tid >> 6;
    const int wm = w >> 1, wn = w & 1;
    const int l15 = lane & 15, quad = lane >> 4;
    const size_t rowbase = (size_t)blockIdx.y * 128;
    const size_t colbase = (size_t)blockIdx.x * 128;
    f32x4v acc[4][4] = {};
    const int rsub = lane >> 3;
    const int schunk = lane & 7;
    const int gchunk = schunk ^ rsub;
    const bf16* Ag = A + (rowbase + w * 32 + rsub) * (size_t)K + gchunk * 8;
    const bf16* Wg = W + (colbase + w * 32 + rsub) * (size_t)K + gchunk * 8;
    bf16* Asl = &As[w * 32][0];
    bf16* Bsl = &Bs[w * 32][0];
    const int swz = l15 & 7;
    for (int k0 = 0; k0 < K; k0 += 64) {
        __syncthreads();
#pragma unroll
        for (int i = 0; i < 4; ++i) {
            async16(Ag + k0 + (size_t)(i * 8) * K, Asl + i * 512);
            async16(Wg + k0 + (size_t)(i * 8) * K, Bsl + i * 512);
        }
        __syncthreads();
#pragma unroll
        for (int kk = 0; kk < 2; ++kk) {
            const int q = kk * 4 + quad;
            bf16x8 af[4], bv[4];
#pragma unroll
            for (int f = 0; f < 4; ++f) {
                af[f] = *(const bf16x8*)&As[wm * 64 + f * 16 + l15][(q ^ swz) * 8];
                bv[f] = *(const bf16x8*)&Bs[wn * 64 + f * 16 + l15][(q ^ swz) * 8];
            }
#pragma unroll
            for (int fm = 0; fm < 4; ++fm)
#pragma unroll
                for (int fn = 0; fn < 4; ++fn)
                    acc[fm][fn] = __builtin_amdgcn_mfma_f32_16x16x32_bf16(af[fm], bv[fn], acc[fm][fn], 0, 0, 0);
        }
    }
    float bcol[4];
    if (MODE == 1 || MODE == 2) {
#pragma unroll
        for (int fn = 0; fn < 4; ++fn) bcol[fn] = bias[colbase + wn * 64 + fn * 16 + l15];
    }
#pragma unroll
    for (int fm = 0; fm < 4; ++fm) {
#pragma unroll
        for (int r = 0; r < 4; ++r) {
            const size_t row = rowbase + wm * 64 + fm * 16 + quad * 4 + r;
            const size_t base = row * (size_t)Nc + colbase + wn * 64 + l15;
#pragma unroll
            for (int fn = 0; fn < 4; ++fn) {
                float v = acc[fm][fn][r];
                const size_t idx = base + fn * 16;
                if (MODE == 0) {
                    outB[idx] = (bf16)v;
                } else if (MODE == 1) {
                    v += bcol[fn];
                    outB[idx] = (bf16)fmaxf(v, 0.f);
                } else if (MODE == 2) {
                    v += bcol[fn] + add1[idx] + add2[idx];
                    outF[idx] = v;
                } else {
                    const size_t t = row & (T_SZ - 1);
                    const size_t col = colbase + wn * 64 + fn * 16 + l15;
                    v += add1[t * (size_t)Nc + col];
                    outF[idx] = v;
                }
            }
        }
    }
}

// ---------------------------------------------------------------- GEMM 256x256, BK=64, 8 waves,
// double-buffered LDS (128 KiB), prefetch issued BEFORE compute so the barrier's vmcnt(0) drain
// lands after the 64-MFMA cluster. One __syncthreads per K-step.
// MODE 1 only in use: +bias, relu, bf16 out.
template <int MODE>
__global__ __launch_bounds__(512, 2) void gemm256_bt(const bf16* __restrict__ A,
                                                     const bf16* __restrict__ W,
                                                     const float* __restrict__ bias,
                                                     float* outF, bf16* outB, int K, int Nc) {
    __shared__ __align__(16) bf16 As[2][256][64];
    __shared__ __align__(16) bf16 Bs[2][256][64];
    const int tid = threadIdx.x;
    const int lane = tid & 63, w = tid >> 6;       // 8 waves
    const int wm = w >> 2, wn = w & 3;             // 2M x 4N wave grid: per-wave C = 128x64
    const int l15 = lane & 15, quad = lane >> 4;
    const size_t rowbase = (size_t)blockIdx.y * 256;
    const size_t colbase = (size_t)blockIdx.x * 256;
    f32x4v acc[8][4] = {};
    const int rsub = lane >> 3;
    const int schunk = lane & 7;
    const int gchunk = schunk ^ rsub;              // pre-swizzled global chunk
    const bf16* Ag = A + (rowbase + w * 32 + rsub) * (size_t)K + gchunk * 8;
    const bf16* Wg = W + (colbase + w * 32 + rsub) * (size_t)K + gchunk * 8;
    const int swz = l15 & 7;
    const int nk = K / 64;
    // prologue: stage K-tile 0 into buffer 0
#pragma unroll
    for (int i = 0; i < 4; ++i) {
        async16(Ag + (size_t)(i * 8) * K, &As[0][w * 32][0] + i * 512);
        async16(Wg + (size_t)(i * 8) * K, &Bs[0][w * 32][0] + i * 512);
    }
    __syncthreads();  // vmcnt(0) drain: tile 0 resident
    for (int t = 0; t < nk; ++t) {
        const int cur = t & 1;
        if (t + 1 < nk) {  // issue next tile's loads BEFORE compute — full-phase overlap
            const size_t ko = (size_t)(t + 1) * 64;
#pragma unroll
            for (int i = 0; i < 4; ++i) {
                async16(Ag + ko + (size_t)(i * 8) * K, &As[cur ^ 1][w * 32][0] + i * 512);
                async16(Wg + ko + (size_t)(i * 8) * K, &Bs[cur ^ 1][w * 32][0] + i * 512);
            }
        }
        __builtin_amdgcn_s_setprio(1);
#pragma unroll
        for (int kk = 0; kk < 2; ++kk) {
            const int q = kk * 4 + quad;
            bf16x8 af[8], bv[4];
#pragma unroll
            for (int f = 0; f < 8; ++f)
                af[f] = *(const bf16x8*)&As[cur][wm * 128 + f * 16 + l15][(q ^ swz) * 8];
#pragma unroll
            for (int f = 0; f < 4; ++f)
                bv[f] = *(const bf16x8*)&Bs[cur][wn * 64 + f * 16 + l15][(q ^ swz) * 8];
#pragma unroll
            for (int fm = 0; fm < 8; ++fm)
#pragma unroll
                for (int fn = 0; fn < 4; ++fn)
                    acc[fm][fn] = __builtin_amdgcn_mfma_f32_16x16x32_bf16(af[fm], bv[fn], acc[fm][fn], 0, 0, 0);
        }
        __builtin_amdgcn_s_setprio(0);
        __syncthreads();
    }
    float bcol[4];
    if (MODE == 1) {
#pragma unroll
        for (int fn = 0; fn < 4; ++fn) bcol[fn] = bias[colbase + wn * 64 + fn * 16 + l15];
    }
#pragma unroll
    for (int fm = 0; fm < 8; ++fm) {
#pragma unroll
        for (int r = 0; r < 4; ++r) {
            const size_t row = rowbase + wm * 128 + fm * 16 + quad * 4 + r;
            const size_t base = row * (size_t)Nc + colbase + wn * 64 + l15;
#pragma unroll
            for (int fn = 0; fn < 4; ++fn) {
                float v = acc[fm][fn][r];
                const size_t idx = base + fn * 16;
                if (MODE == 1) {
                    v += bcol[fn];
                    outB[idx] = (bf16)fmaxf(v, 0.f);
                } else {
                    outF[idx] = v;
                }
            }
        }
    }
}

// ---------------------------------------------------------------- MFMA flash attention (S^T formulation)
// CAUSAL-PAIRED grid (T/256, H, B): block `pair` processes strips {pair, NQT-1-pair}
// sequentially -> uniform 34 K-tiles per block (fixes the 11%-occupancy imbalance tail:
// measured 226us/dispatch, MfmaUtil 6%, Occupancy 11% at the old 16-strip grid).
// 4 waves; wave w owns q rows [w*32, w*32+32) of each strip.
// S^T = mfma(A=K, B=Q): lane holds S^T[s=quad*4+r][q=l15]; softmax via shfl_xor(16,32);
// P through LDS as b64; K/V register-prefetched one tile ahead; LDS layouts bank-uniform.
__global__ __launch_bounds__(256) void attn_kernel(const bf16* __restrict__ qkv,
                                                   const float* __restrict__ x,
                                                   float* __restrict__ h) {
    constexpr int NQT = T_SZ / 128;
    const int pair = blockIdx.x;  // 0..NQT/2-1
    const int hh = blockIdx.y, b = blockIdx.z;
    const int tid = threadIdx.x;
    const int lane = tid & 63, w = tid >> 6;
    const int quad = lane >> 4, l15 = lane & 15;

    __shared__ __align__(16) bf16 Ks[64][64];     // XOR-swizzled chunks
    __shared__ __align__(16) bf16 Vt[64][72];     // [ch][s]
    __shared__ __align__(16) bf16 Ps[4][16][80];  // per-wave P: [q][s], pad 80

    constexpr float SC = 0.125f * 1.44269504f;  // scale * log2(e)

    // staging geometry (strip-invariant)
    const int krow = lane >> 3;          // 0..7 within 8-row group
    const int kchunk = lane & 7;         // global 16B chunk
    const int kswz = kchunk ^ krow;      // LDS chunk (XOR swizzle)
    const bf16* kbase = qkv + ((size_t)(b * T_SZ) + w * 16 + krow) * QKV_LD +
                        hh * 192 + 64 + kchunk * 8;
    const bf16* vbase0 = qkv + ((size_t)(b * T_SZ) + w * 8) * QKV_LD + hh * 192 + 128 + lane;
    const bf16* vbase1 = qkv + ((size_t)(b * T_SZ) + (w + 4) * 8) * QKV_LD + hh * 192 + 128 + lane;

    for (int half = 0; half < 2; ++half) {
        const int qt = half ? (NQT - 1 - pair) : pair;
        const int qwave = qt * 128 + w * 32;
        const int nst = 2 * qt + 2;

        // Q fragments: B-frag [n=q=l15][k=ch]
        bf16x8 Qf[2][2];
#pragma unroll
        for (int qsub = 0; qsub < 2; ++qsub)
#pragma unroll
            for (int kc = 0; kc < 2; ++kc)
                Qf[qsub][kc] = *(const bf16x8*)(qkv +
                    ((size_t)(b * T_SZ + qt * 128 + w * 32 + qsub * 16 + l15)) * QKV_LD +
                    hh * 192 + kc * 32 + quad * 8);

        f32x4v accO[2][4] = {};
        float m_[2] = {-1e30f, -1e30f}, l_[2] = {0.f, 0.f};

        const bf16* kptr = kbase;
        const bf16* vptr0 = vbase0;
        const bf16* vptr1 = vbase1;

        // prologue prefetch (tile 0)
        uint4 kr0 = *(const uint4*)(kptr);
        uint4 kr1 = *(const uint4*)(kptr + (size_t)8 * QKV_LD);
        bf16x8 vv0, vv1;
#pragma unroll
        for (int j = 0; j < 8; ++j) { vv0[j] = vptr0[(size_t)j * QKV_LD]; vv1[j] = vptr1[(size_t)j * QKV_LD]; }
        kptr += (size_t)64 * QKV_LD; vptr0 += (size_t)64 * QKV_LD; vptr1 += (size_t)64 * QKV_LD;

        for (int st = 0; st < nst; ++st) {
            const int sbase = st * 64;
            __syncthreads();  // protect Ks/Vt against previous tile's readers
            *(uint4*)&Ks[w * 16 + krow][kswz * 8] = kr0;
            *(uint4*)&Ks[w * 16 + 8 + krow][kswz * 8] = kr1;
            *(bf16x8*)&Vt[lane][w * 8] = vv0;
            *(bf16x8*)&Vt[lane][(w + 4) * 8] = vv1;
            __syncthreads();
            if (st + 1 < nst) {  // prefetch next tile (overlaps compute below)
                kr0 = *(const uint4*)(kptr);
                kr1 = *(const uint4*)(kptr + (size_t)8 * QKV_LD);
#pragma unroll
                for (int j = 0; j < 8; ++j) { vv0[j] = vptr0[(size_t)j * QKV_LD]; vv1[j] = vptr1[(size_t)j * QKV_LD]; }
                kptr += (size_t)64 * QKV_LD; vptr0 += (size_t)64 * QKV_LD; vptr1 += (size_t)64 * QKV_LD;
            }
            if (sbase <= qwave + 31) {
#pragma unroll
                for (int qsub = 0; qsub < 2; ++qsub) {
                    const int qb = qwave + qsub * 16;  // q = qb + l15
                    // --- S^T = K Q^T ---
                    f32x4v St[4] = {};
                    __builtin_amdgcn_s_setprio(1);
#pragma unroll
                    for (int ssub = 0; ssub < 4; ++ssub)
#pragma unroll
                        for (int kc = 0; kc < 2; ++kc) {
                            bf16x8 Kf = *(const bf16x8*)&Ks[ssub * 16 + l15][((kc * 4 + quad) ^ (l15 & 7)) * 8];
                            St[ssub] = __builtin_amdgcn_mfma_f32_16x16x32_bf16(Kf, Qf[qsub][kc], St[ssub], 0, 0, 0);
                        }
                    __builtin_amdgcn_s_setprio(0);
                    // --- scale to log2 domain + causal mask ---
                    float sv[4][4];
#pragma unroll
                    for (int ssub = 0; ssub < 4; ++ssub)
#pragma unroll
                        for (int r = 0; r < 4; ++r) sv[ssub][r] = St[ssub][r] * SC;
                    if (sbase + 63 > qb) {
#pragma unroll
                        for (int ssub = 0; ssub < 4; ++ssub) {
#pragma unroll
                            for (int r = 0; r < 4; ++r) {
                                const int s = sbase + ssub * 16 + quad * 4 + r;
                                if (s > qb + l15) sv[ssub][r] = -1e38f;
                            }
                        }
                    }
                    // --- online softmax per q (=l15), cross-quad via shfl 16/32 ---
                    float mx = sv[0][0];
#pragma unroll
                    for (int ssub = 0; ssub < 4; ++ssub)
#pragma unroll
                        for (int r = 0; r < 4; ++r) mx = fmaxf(mx, sv[ssub][r]);
                    mx = fmaxf(mx, __shfl_xor(mx, 16));
                    mx = fmaxf(mx, __shfl_xor(mx, 32));
                    const float mold = m_[qsub];
                    const float mnew = fmaxf(mold, mx);
                    const float al = exp2f(mold - mnew);
                    float rs = 0.f;
                    float p[4][4];
#pragma unroll
                    for (int ssub = 0; ssub < 4; ++ssub)
#pragma unroll
                        for (int r = 0; r < 4; ++r) {
                            p[ssub][r] = exp2f(sv[ssub][r] - mnew);
                            rs += p[ssub][r];
                        }
                    rs += __shfl_xor(rs, 16);
                    rs += __shfl_xor(rs, 32);
                    l_[qsub] = l_[qsub] * al + rs;
                    m_[qsub] = mnew;
                    // --- store P (b64, bank-uniform) ---
#pragma unroll
                    for (int ssub = 0; ssub < 4; ++ssub) {
                        bf16x4 pk;
#pragma unroll
                        for (int r = 0; r < 4; ++r) pk[r] = (bf16)p[ssub][r];
                        *(bf16x4*)&Ps[w][l15][ssub * 16 + quad * 4] = pk;
                    }
                    // --- realign alpha to PV C-layout rows & rescale O ---
                    float alr[4];
#pragma unroll
                    for (int r = 0; r < 4; ++r) alr[r] = __shfl(al, quad * 4 + r);
#pragma unroll
                    for (int nsub = 0; nsub < 4; ++nsub)
#pragma unroll
                        for (int r = 0; r < 4; ++r) accO[qsub][nsub][r] *= alr[r];
                    // --- O += P V ---
                    __builtin_amdgcn_s_setprio(1);
#pragma unroll
                    for (int kc2 = 0; kc2 < 2; ++kc2) {
                        bf16x8 Pf = *(const bf16x8*)&Ps[w][l15][kc2 * 32 + quad * 8];
#pragma unroll
                        for (int nsub = 0; nsub < 4; ++nsub) {
                            bf16x8 Vf = *(const bf16x8*)&Vt[nsub * 16 + l15][kc2 * 32 + quad * 8];
                            accO[qsub][nsub] =
                                __builtin_amdgcn_mfma_f32_16x16x32_bf16(Pf, Vf, accO[qsub][nsub], 0, 0, 0);
                        }
                    }
                    __builtin_amdgcn_s_setprio(0);
                }
            }
        }
        // --- epilogue: h = x + O / l ---
#pragma unroll
        for (int qsub = 0; qsub < 2; ++qsub) {
            const float linv = 1.f / l_[qsub];
            float invr[4];
#pragma unroll
            for (int r = 0; r < 4; ++r) invr[r] = __shfl(linv, quad * 4 + r);
#pragma unroll
            for (int r = 0; r < 4; ++r) {
                const size_t row = (size_t)(b * T_SZ + qt * 128 + w * 32 + qsub * 16 + quad * 4 + r);
                const size_t base = row * D_DIM + (size_t)hh * 64 + l15;
#pragma unroll
                for (int nsub = 0; nsub < 4; ++nsub) {
                    const size_t idx = base + nsub * 16;
                    h[idx] = x[idx] + accO[qsub][nsub][r] * invr[r];
                }
            }
        }
    }
}

// ---------------------------------------------------------------- unembed MFMA: out[M,64] = A[M,1024] @ W[64,1024]^T + bun
__global__ __launch_bounds__(256) void unembed_kernel(const bf16* __restrict__ A,
                                                      const bf16* __restrict__ W,
                                                      const float* __restrict__ bun,
                                                      float* __restrict__ out) {
    __shared__ __align__(16) bf16 As[128][64];
    __shared__ __align__(16) bf16 Ws[64][64];
    const int tid = threadIdx.x, lane = tid & 63, w = tid >> 6;
    const int l15 = lane & 15, quad = lane >> 4;
    const size_t rowbase = (size_t)blockIdx.x * 128;
    const int rsub = lane >> 3, schunk = lane & 7, gchunk = schunk ^ rsub;
    const bf16* Ag = A + (rowbase + w * 32 + rsub) * (size_t)D_DIM + gchunk * 8;
    const bf16* Wg = W + (w * 16 + rsub) * (size_t)D_DIM + gchunk * 8;
    bf16* Asl = &As[w * 32][0];
    bf16* Wsl = &Ws[w * 16][0];
    const int swz = l15 & 7;
    f32x4v acc[2][4] = {};
    for (int k0 = 0; k0 < D_DIM; k0 += 64) {
        __syncthreads();
#pragma unroll
        for (int i = 0; i < 4; ++i)
            async16(Ag + k0 + (size_t)(i * 8) * D_DIM, Asl + i * 512);
#pragma unroll
        for (int i = 0; i < 2; ++i)
            async16(Wg + k0 + (size_t)(i * 8) * D_DIM, Wsl + i * 512);
        __syncthreads();
#pragma unroll
        for (int kk = 0; kk < 2; ++kk) {
            const int q = kk * 4 + quad;
            bf16x8 af[2], bv[4];
#pragma unroll
            for (int f = 0; f < 2; ++f) af[f] = *(const bf16x8*)&As[w * 32 + f * 16 + l15][(q ^ swz) * 8];
#pragma unroll
            for (int f = 0; f < 4; ++f) bv[f] = *(const bf16x8*)&Ws[f * 16 + l15][(q ^ swz) * 8];
#pragma unroll
            for (int fm = 0; fm < 2; ++fm)
#pragma unroll
                for (int fn = 0; fn < 4; ++fn)
                    acc[fm][fn] = __builtin_amdgcn_mfma_f32_16x16x32_bf16(af[fm], bv[fn], acc[fm][fn], 0, 0, 0);
        }
    }
#pragma unroll
    for (int fm = 0; fm < 2; ++fm)
#pragma unroll
        for (int r = 0; r < 4; ++r) {
            const size_t row = rowbase + w * 32 + fm * 16 + quad * 4 + r;
#pragma unroll
            for (int fn = 0; fn < 4; ++fn) {
                const int col = fn * 16 + l15;
                out[row * V_DIM + col] = acc[fm][fn][r] + bun[col];
            }
        }
}

// ---------------------------------------------------------------- host
extern "C" void kernel_launch(void* const* d_in, const int* in_sizes, int n_in,
                              void* d_out, int out_size, void* d_ws, size_t ws_size,
                              hipStream_t stream) {
    (void)in_sizes; (void)n_in; (void)out_size;
    const float* toks = (const float*)d_in[0];
    const float* wtok = (const float*)d_in[1];
    const float* wpos = (const float*)d_in[2];
    const float* wqkv = (const float*)d_in[3];
    const float* g1   = (const float*)d_in[4];
    const float* be1  = (const float*)d_in[5];
    const float* w1   = (const float*)d_in[6];
    const float* bm1  = (const float*)d_in[7];
    const float* w2   = (const float*)d_in[8];
    const float* bm2  = (const float*)d_in[9];
    const float* g2   = (const float*)d_in[10];
    const float* be2  = (const float*)d_in[11];
    const float* gf   = (const float*)d_in[12];
    const float* bfp  = (const float*)d_in[13];
    const float* wun  = (const float*)d_in[14];
    const float* bun  = (const float*)d_in[15];
    float* out = (float*)d_out;

    char* ws = (char*)d_ws;
    size_t off = 0;
    auto take = [&](size_t n) { char* p = ws + off; off += (n + 255) & ~(size_t)255; return p; };
    float* xf   = (float*)take((size_t)N_TOK * D_DIM * 4);
    float* hf   = (float*)take((size_t)N_TOK * D_DIM * 4);
    bf16* lnb   = (bf16*)take((size_t)N_TOK * D_DIM * 2);
    bf16* qkvb  = (bf16*)take((size_t)N_TOK * 3 * D_DIM * 2);
    bf16* a1b   = (bf16*)take((size_t)N_TOK * M_DIM * 2);
    bf16* toksb = (bf16*)take((size_t)N_TOK * V_DIM * 2);
    bf16* wtokb = (bf16*)take((size_t)D_DIM * V_DIM * 2);
    bf16* wunb  = (bf16*)take((size_t)V_DIM * D_DIM * 2);
    float* posT = (float*)take((size_t)TMAXP * D_DIM * 4);

    const size_t perL_q = (size_t)3 * D_DIM * D_DIM;   // elems
    const size_t perL_1 = (size_t)M_DIM * D_DIM;
    const size_t perL_2 = (size_t)D_DIM * M_DIM;
    const size_t all_bytes = (size_t)L_NUM * (perL_q + perL_1 + perL_2) * 2 + 4096;
    const bool pre = (ws_size > off) && (ws_size - off >= all_bytes);

    bf16 *wqb, *w1b, *w2b;
    if (pre) {
        wqb = (bf16*)take((size_t)L_NUM * perL_q * 2);
        w1b = (bf16*)take((size_t)L_NUM * perL_1 * 2);
        w2b = (bf16*)take((size_t)L_NUM * perL_2 * 2);
    } else {
        wqb = (bf16*)take(perL_q * 2);
        w1b = (bf16*)take(perL_1 * 2);
        w2b = (bf16*)take(perL_2 * 2);
    }

    convert_kernel<<<(N_TOK * V_DIM) / 1024, 256, 0, stream>>>(toks, toksb, N_TOK * V_DIM);
    convert_kernel<<<(D_DIM * V_DIM) / 1024, 256, 0, stream>>>(wtok, wtokb, D_DIM * V_DIM);
    transpose_pos<<<dim3(TMAXP / 32, D_DIM / 32), 256, 0, stream>>>(wpos, posT);
    gemm_bt<3><<<dim3(D_DIM / 128, N_TOK / 128), 256, 0, stream>>>(
        toksb, wtokb, nullptr, posT, nullptr, xf, nullptr, V_DIM, D_DIM);

    if (pre) {  // hoist all weight converts out of the layer loop (3 launches instead of 24)
        convert_kernel<<<(int)((L_NUM * perL_q) / 1024), 256, 0, stream>>>(
            wqkv, wqb, (int)(L_NUM * perL_q));
        convert_kernel<<<(int)((L_NUM * perL_1) / 1024), 256, 0, stream>>>(
            w1, w1b, (int)(L_NUM * perL_1));
        convert_kernel<<<(int)((L_NUM * perL_2) / 1024), 256, 0, stream>>>(
            w2, w2b, (int)(L_NUM * perL_2));
    }

    for (int l = 0; l < L_NUM; ++l) {
        bf16* wq_l = pre ? wqb + (size_t)l * perL_q : wqb;
        bf16* w1_l = pre ? w1b + (size_t)l * perL_1 : w1b;
        bf16* w2_l = pre ? w2b + (size_t)l * perL_2 : w2b;
        if (!pre)
            convert_kernel<<<(int)(perL_q / 1024), 256, 0, stream>>>(
                wqkv + (size_t)l * perL_q, wq_l, (int)perL_q);
        ln_kernel<<<N_TOK, 256, 0, stream>>>(xf, g1 + l * D_DIM, be1 + l * D_DIM, lnb);
        gemm_bt<0><<<dim3(3 * D_DIM / 128, N_TOK / 128), 256, 0, stream>>>(
            lnb, wq_l, nullptr, nullptr, nullptr, nullptr, qkvb, D_DIM, 3 * D_DIM);
        // causal-paired attention: uniform 34 K-tiles per block, 512 blocks
        attn_kernel<<<dim3(T_SZ / 256, H_NUM, B_SZ), 256, 0, stream>>>(qkvb, xf, hf);
        ln_kernel<<<N_TOK, 256, 0, stream>>>(hf, g2 + l * D_DIM, be2 + l * D_DIM, lnb);
        if (!pre)
            convert_kernel<<<(int)(perL_1 / 1024), 256, 0, stream>>>(
                w1 + (size_t)l * perL_1, w1_l, (int)perL_1);
        // MLP1: 256x256 double-buffered GEMM — grid 16x32 = 512 blocks.
        gemm256_bt<1><<<dim3(M_DIM / 256, N_TOK / 256), 512, 0, stream>>>(
            lnb, w1_l, bm1 + l * M_DIM, nullptr, a1b, D_DIM, M_DIM);
        if (!pre)
            convert_kernel<<<(int)(perL_2 / 1024), 256, 0, stream>>>(
                w2 + (size_t)l * perL_2, w2_l, (int)perL_2);
        gemm_bt<2><<<dim3(D_DIM / 128, N_TOK / 128), 256, 0, stream>>>(
            a1b, w2_l, bm2 + l * D_DIM, xf, hf, xf, nullptr, M_DIM, D_DIM);
    }
    ln_kernel<<<N_TOK, 256, 0, stream>>>(xf, gf, bfp, lnb);
    convert_kernel<<<(V_DIM * D_DIM) / 1024, 256, 0, stream>>>(wun, wunb, V_DIM * D_DIM);
    unembed_kernel<<<N_TOK / 128, 256, 0, stream>>>(lnb, wunb, bun, out);
}

// Round 12
// 3359.747 us; speedup vs baseline: 1.3159x; 1.0663x over previous
//
#include <hip/hip_runtime.h>
#include <cstdint>
#include <cstddef>

#define L_NUM 8
#define D_DIM 1024
#define H_NUM 16
#define C_DIM 64
#define M_DIM 4096
#define V_DIM 64
#define B_SZ 4
#define T_SZ 2048
#define N_TOK (B_SZ * T_SZ)
#define TMAXP 2048
#define QKV_LD (3 * D_DIM)

typedef __bf16 bf16;
typedef bf16 bf16x4 __attribute__((ext_vector_type(4)));
typedef bf16 bf16x8 __attribute__((ext_vector_type(8)));
typedef float f32x4v __attribute__((ext_vector_type(4)));

// async global->LDS, 16B per lane. LDS dest = wave-uniform base + lane*16.
__device__ __forceinline__ void async16(const bf16* g, bf16* l) {
    __builtin_amdgcn_global_load_lds(
        (const __attribute__((address_space(1))) void*)g,
        (__attribute__((address_space(3))) void*)l, 16, 0, 0);
}

// XCD-aware block->tile swizzle (T1): HW dispatches linear block id round-robin
// across 8 XCDs; remap so XCD x processes a CONTIGUOUS tile range (consecutive
// row-slabs) -> A-slab fetched once per XCD L2. Bijective iff nwg % 8 == 0
// (all call sites: 1536 / 512 / 512). Pure tile permutation: correctness-neutral.
__device__ __forceinline__ void xcd_swz(int& bx, int& by) {
    const int gx = (int)gridDim.x;
    const int nwg = gx * (int)gridDim.y;
    int lin = (int)blockIdx.y * gx + (int)blockIdx.x;
    lin = (lin & 7) * (nwg >> 3) + (lin >> 3);
    by = lin / gx;
    bx = lin - by * gx;
}

// ---------------------------------------------------------------- convert f32 -> bf16
__global__ __launch_bounds__(256) void convert_kernel(const float* __restrict__ src,
                                                      bf16* __restrict__ dst, int n) {
    int i = (blockIdx.x * 256 + threadIdx.x) * 4;
    if (i >= n) return;
    const float4 v = *(const float4*)(src + i);
    bf16x4 o;
    o[0] = (bf16)v.x; o[1] = (bf16)v.y; o[2] = (bf16)v.z; o[3] = (bf16)v.w;
    *(bf16x4*)(dst + i) = o;
}

// ---------------------------------------------------------------- wpos [D][TMAX] -> posT [TMAX][D]
__global__ __launch_bounds__(256) void transpose_pos(const float* __restrict__ in,
                                                     float* __restrict__ out) {
    __shared__ float tile[32][33];
    const int t0 = blockIdx.x * 32, d0 = blockIdx.y * 32;
    const int tx = threadIdx.x & 31, ty = threadIdx.x >> 5;
#pragma unroll
    for (int j = 0; j < 32; j += 8)
        tile[ty + j][tx] = in[(size_t)(d0 + ty + j) * TMAXP + t0 + tx];
    __syncthreads();
#pragma unroll
    for (int j = 0; j < 32; j += 8)
        out[(size_t)(t0 + ty + j) * D_DIM + d0 + tx] = tile[tx][ty + j];
}

// ---------------------------------------------------------------- layernorm (fp32 in, bf16 out)
__global__ __launch_bounds__(256) void ln_kernel(const float* __restrict__ x,
                                                 const float* __restrict__ g,
                                                 const float* __restrict__ b,
                                                 bf16* __restrict__ y) {
    const int n = blockIdx.x, tid = threadIdx.x;
    const float4 v = ((const float4*)(x + (size_t)n * D_DIM))[tid];
    float s = v.x + v.y + v.z + v.w;
    float q = v.x * v.x + v.y * v.y + v.z * v.z + v.w * v.w;
#pragma unroll
    for (int off = 32; off > 0; off >>= 1) {
        s += __shfl_xor(s, off);
        q += __shfl_xor(q, off);
    }
    __shared__ float s1[4], s2[4];
    if ((tid & 63) == 0) { s1[tid >> 6] = s; s2[tid >> 6] = q; }
    __syncthreads();
    s = s1[0] + s1[1] + s1[2] + s1[3];
    q = s2[0] + s2[1] + s2[2] + s2[3];
    const float mu = s * (1.f / D_DIM);
    const float var = q * (1.f / D_DIM) - mu * mu;
    const float rs = rsqrtf(var + 1e-5f);
    const float4 gg = ((const float4*)g)[tid];
    const float4 bb = ((const float4*)b)[tid];
    bf16x4 o;
    o[0] = (bf16)((v.x - mu) * rs * gg.x + bb.x);
    o[1] = (bf16)((v.y - mu) * rs * gg.y + bb.y);
    o[2] = (bf16)((v.z - mu) * rs * gg.z + bb.z);
    o[3] = (bf16)((v.w - mu) * rs * gg.w + bb.w);
    ((bf16x4*)(y + (size_t)n * D_DIM))[tid] = o;
}

// ---------------------------------------------------------------- GEMM: C[M,N] = A[M,K] @ W[N,K]^T
// 128x128 tile, BK=64, global_load_lds width-16 staging with XOR-8 chunk swizzle.
// XCD-swizzled block->tile map (T1). MODE 0: store bf16. MODE 1: +bias, relu, bf16.
// MODE 2: +bias+add1+add2, f32. MODE 3: +posT[(row%T)*Nc+col] (add1=posT), f32.
template <int MODE>
__global__ __launch_bounds__(256) void gemm_bt(const bf16* __restrict__ A,
                                               const bf16* __restrict__ W,
                                               const float* __restrict__ bias,
                                               const float* add1, const float* add2,
                                               float* outF, bf16* outB, int K, int Nc) {
    __shared__ __align__(16) bf16 As[128][64];
    __shared__ __align__(16) bf16 Bs[128][64];
    const int tid = threadIdx.x;
    const int lane = tid & 63, w = tid >> 6;
    const int wm = w >> 1, wn = w & 1;
    const int l15 = lane & 15, quad = lane >> 4;
    int bx, by;
    xcd_swz(bx, by);
    const size_t rowbase = (size_t)by * 128;
    const size_t colbase = (size_t)bx * 128;
    f32x4v acc[4][4] = {};
    const int rsub = lane >> 3;
    const int schunk = lane & 7;
    const int gchunk = schunk ^ rsub;
    const bf16* Ag = A + (rowbase + w * 32 + rsub) * (size_t)K + gchunk * 8;
    const bf16* Wg = W + (colbase + w * 32 + rsub) * (size_t)K + gchunk * 8;
    bf16* Asl = &As[w * 32][0];
    bf16* Bsl = &Bs[w * 32][0];
    const int swz = l15 & 7;
    for (int k0 = 0; k0 < K; k0 += 64) {
        __syncthreads();
#pragma unroll
        for (int i = 0; i < 4; ++i) {
            async16(Ag + k0 + (size_t)(i * 8) * K, Asl + i * 512);
            async16(Wg + k0 + (size_t)(i * 8) * K, Bsl + i * 512);
        }
        __syncthreads();
#pragma unroll
        for (int kk = 0; kk < 2; ++kk) {
            const int q = kk * 4 + quad;
            bf16x8 af[4], bv[4];
#pragma unroll
            for (int f = 0; f < 4; ++f) {
                af[f] = *(const bf16x8*)&As[wm * 64 + f * 16 + l15][(q ^ swz) * 8];
                bv[f] = *(const bf16x8*)&Bs[wn * 64 + f * 16 + l15][(q ^ swz) * 8];
            }
#pragma unroll
            for (int fm = 0; fm < 4; ++fm)
#pragma unroll
                for (int fn = 0; fn < 4; ++fn)
                    acc[fm][fn] = __builtin_amdgcn_mfma_f32_16x16x32_bf16(af[fm], bv[fn], acc[fm][fn], 0, 0, 0);
        }
    }
    float bcol[4];
    if (MODE == 1 || MODE == 2) {
#pragma unroll
        for (int fn = 0; fn < 4; ++fn) bcol[fn] = bias[colbase + wn * 64 + fn * 16 + l15];
    }
#pragma unroll
    for (int fm = 0; fm < 4; ++fm) {
#pragma unroll
        for (int r = 0; r < 4; ++r) {
            const size_t row = rowbase + wm * 64 + fm * 16 + quad * 4 + r;
            const size_t base = row * (size_t)Nc + colbase + wn * 64 + l15;
#pragma unroll
            for (int fn = 0; fn < 4; ++fn) {
                float v = acc[fm][fn][r];
                const size_t idx = base + fn * 16;
                if (MODE == 0) {
                    outB[idx] = (bf16)v;
                } else if (MODE == 1) {
                    v += bcol[fn];
                    outB[idx] = (bf16)fmaxf(v, 0.f);
                } else if (MODE == 2) {
                    v += bcol[fn] + add1[idx] + add2[idx];
                    outF[idx] = v;
                } else {
                    const size_t t = row & (T_SZ - 1);
                    const size_t col = colbase + wn * 64 + fn * 16 + l15;
                    v += add1[t * (size_t)Nc + col];
                    outF[idx] = v;
                }
            }
        }
    }
}

// ---------------------------------------------------------------- GEMM 256x256, BK=64, 8 waves,
// double-buffered LDS (128 KiB), prefetch issued BEFORE compute so the barrier's vmcnt(0) drain
// lands after the 64-MFMA cluster. One __syncthreads per K-step. XCD-swizzled tile map.
// MODE 1 only in use: +bias, relu, bf16 out.
template <int MODE>
__global__ __launch_bounds__(512, 2) void gemm256_bt(const bf16* __restrict__ A,
                                                     const bf16* __restrict__ W,
                                                     const float* __restrict__ bias,
                                                     float* outF, bf16* outB, int K, int Nc) {
    __shared__ __align__(16) bf16 As[2][256][64];
    __shared__ __align__(16) bf16 Bs[2][256][64];
    const int tid = threadIdx.x;
    const int lane = tid & 63, w = tid >> 6;       // 8 waves
    const int wm = w >> 2, wn = w & 3;             // 2M x 4N wave grid: per-wave C = 128x64
    const int l15 = lane & 15, quad = lane >> 4;
    int bx, by;
    xcd_swz(bx, by);
    const size_t rowbase = (size_t)by * 256;
    const size_t colbase = (size_t)bx * 256;
    f32x4v acc[8][4] = {};
    const int rsub = lane >> 3;
    const int schunk = lane & 7;
    const int gchunk = schunk ^ rsub;              // pre-swizzled global chunk
    const bf16* Ag = A + (rowbase + w * 32 + rsub) * (size_t)K + gchunk * 8;
    const bf16* Wg = W + (colbase + w * 32 + rsub) * (size_t)K + gchunk * 8;
    const int swz = l15 & 7;
    const int nk = K / 64;
    // prologue: stage K-tile 0 into buffer 0
#pragma unroll
    for (int i = 0; i < 4; ++i) {
        async16(Ag + (size_t)(i * 8) * K, &As[0][w * 32][0] + i * 512);
        async16(Wg + (size_t)(i * 8) * K, &Bs[0][w * 32][0] + i * 512);
    }
    __syncthreads();  // vmcnt(0) drain: tile 0 resident
    for (int t = 0; t < nk; ++t) {
        const int cur = t & 1;
        if (t + 1 < nk) {  // issue next tile's loads BEFORE compute — full-phase overlap
            const size_t ko = (size_t)(t + 1) * 64;
#pragma unroll
            for (int i = 0; i < 4; ++i) {
                async16(Ag + ko + (size_t)(i * 8) * K, &As[cur ^ 1][w * 32][0] + i * 512);
                async16(Wg + ko + (size_t)(i * 8) * K, &Bs[cur ^ 1][w * 32][0] + i * 512);
            }
        }
        __builtin_amdgcn_s_setprio(1);
#pragma unroll
        for (int kk = 0; kk < 2; ++kk) {
            const int q = kk * 4 + quad;
            bf16x8 af[8], bv[4];
#pragma unroll
            for (int f = 0; f < 8; ++f)
                af[f] = *(const bf16x8*)&As[cur][wm * 128 + f * 16 + l15][(q ^ swz) * 8];
#pragma unroll
            for (int f = 0; f < 4; ++f)
                bv[f] = *(const bf16x8*)&Bs[cur][wn * 64 + f * 16 + l15][(q ^ swz) * 8];
#pragma unroll
            for (int fm = 0; fm < 8; ++fm)
#pragma unroll
                for (int fn = 0; fn < 4; ++fn)
                    acc[fm][fn] = __builtin_amdgcn_mfma_f32_16x16x32_bf16(af[fm], bv[fn], acc[fm][fn], 0, 0, 0);
        }
        __builtin_amdgcn_s_setprio(0);
        __syncthreads();
    }
    float bcol[4];
    if (MODE == 1) {
#pragma unroll
        for (int fn = 0; fn < 4; ++fn) bcol[fn] = bias[colbase + wn * 64 + fn * 16 + l15];
    }
#pragma unroll
    for (int fm = 0; fm < 8; ++fm) {
#pragma unroll
        for (int r = 0; r < 4; ++r) {
            const size_t row = rowbase + wm * 128 + fm * 16 + quad * 4 + r;
            const size_t base = row * (size_t)Nc + colbase + wn * 64 + l15;
#pragma unroll
            for (int fn = 0; fn < 4; ++fn) {
                float v = acc[fm][fn][r];
                const size_t idx = base + fn * 16;
                if (MODE == 1) {
                    v += bcol[fn];
                    outB[idx] = (bf16)fmaxf(v, 0.f);
                } else {
                    outF[idx] = v;
                }
            }
        }
    }
}

// ---------------------------------------------------------------- MFMA flash attention (S^T formulation)
// CAUSAL-PAIRED grid (T/256, H, B), 8 WAVES (512 threads): block `pair` processes strips
// {pair, NQT-1-pair} sequentially (uniform 34 K-tiles); wave w owns 16 q-rows
// [w*16, w*16+16) of each strip. 8 waves doubles waves/CU vs the 4-wave version
// (measured: 143us, Occupancy 20.7% == the 2-block/CU x 4-wave grid cap; VALU 47%,
// MFMA 10% -> latency-bound at the cap). LDS 37.9KB -> still 2 blocks/CU -> 16 waves/CU.
// Per-wave body = verbatim qsub=0 slice of the measured-passing kernel.
__global__ __launch_bounds__(512, 4) void attn_kernel(const bf16* __restrict__ qkv,
                                                      const float* __restrict__ x,
                                                      float* __restrict__ h) {
    constexpr int NQT = T_SZ / 128;
    const int pair = blockIdx.x;  // 0..NQT/2-1
    const int hh = blockIdx.y, b = blockIdx.z;
    const int tid = threadIdx.x;
    const int lane = tid & 63, w = tid >> 6;   // 8 waves
    const int quad = lane >> 4, l15 = lane & 15;

    __shared__ __align__(16) bf16 Ks[64][64];     // XOR-swizzled chunks
    __shared__ __align__(16) bf16 Vt[64][72];     // [ch][s]
    __shared__ __align__(16) bf16 Ps[8][16][80];  // per-wave P: [q][s], pad 80

    constexpr float SC = 0.125f * 1.44269504f;  // scale * log2(e)

    // staging geometry (strip-invariant): wave w stages K rows [w*8,w*8+8) and V slots [w*8,w*8+8)
    const int krow = lane >> 3;          // 0..7 within 8-row group
    const int kchunk = lane & 7;         // global 16B chunk
    const int kswz = kchunk ^ krow;      // LDS chunk (XOR swizzle); row&7 == krow
    const bf16* kbase = qkv + ((size_t)(b * T_SZ) + w * 8 + krow) * QKV_LD +
                        hh * 192 + 64 + kchunk * 8;
    const bf16* vbase = qkv + ((size_t)(b * T_SZ) + w * 8) * QKV_LD + hh * 192 + 128 + lane;

    for (int half = 0; half < 2; ++half) {
        const int qt = half ? (NQT - 1 - pair) : pair;
        const int qwave = qt * 128 + w * 16;   // wave's 16 q-rows: [qwave, qwave+16)
        const int nst = 2 * qt + 2;

        // Q fragments: B-frag [n=q=l15][k=ch]
        bf16x8 Qf[2];
#pragma unroll
        for (int kc = 0; kc < 2; ++kc)
            Qf[kc] = *(const bf16x8*)(qkv +
                ((size_t)(b * T_SZ + qwave + l15)) * QKV_LD +
                hh * 192 + kc * 32 + quad * 8);

        f32x4v accO[4] = {};
        float m_ = -1e30f, l_ = 0.f;

        const bf16* kptr = kbase;
        const bf16* vptr = vbase;

        // prologue prefetch (tile 0)
        uint4 kr0 = *(const uint4*)(kptr);
        bf16x8 vv0;
#pragma unroll
        for (int j = 0; j < 8; ++j) vv0[j] = vptr[(size_t)j * QKV_LD];
        kptr += (size_t)64 * QKV_LD; vptr += (size_t)64 * QKV_LD;

        for (int st = 0; st < nst; ++st) {
            const int sbase = st * 64;
            __syncthreads();  // protect Ks/Vt against previous tile's readers
            *(uint4*)&Ks[w * 8 + krow][kswz * 8] = kr0;
            *(bf16x8*)&Vt[lane][w * 8] = vv0;
            __syncthreads();
            if (st + 1 < nst) {  // prefetch next tile (overlaps compute below)
                kr0 = *(const uint4*)(kptr);
#pragma unroll
                for (int j = 0; j < 8; ++j) vv0[j] = vptr[(size_t)j * QKV_LD];
                kptr += (size_t)64 * QKV_LD; vptr += (size_t)64 * QKV_LD;
            }
            if (sbase <= qwave + 15) {
                const int qb = qwave;  // q = qb + l15
                // --- S^T = K Q^T ---
                f32x4v St[4] = {};
                __builtin_amdgcn_s_setprio(1);
#pragma unroll
                for (int ssub = 0; ssub < 4; ++ssub)
#pragma unroll
                    for (int kc = 0; kc < 2; ++kc) {
                        bf16x8 Kf = *(const bf16x8*)&Ks[ssub * 16 + l15][((kc * 4 + quad) ^ (l15 & 7)) * 8];
                        St[ssub] = __builtin_amdgcn_mfma_f32_16x16x32_bf16(Kf, Qf[kc], St[ssub], 0, 0, 0);
                    }
                __builtin_amdgcn_s_setprio(0);
                // --- scale to log2 domain + causal mask ---
                float sv[4][4];
#pragma unroll
                for (int ssub = 0; ssub < 4; ++ssub)
#pragma unroll
                    for (int r = 0; r < 4; ++r) sv[ssub][r] = St[ssub][r] * SC;
                if (sbase + 63 > qb) {
#pragma unroll
                    for (int ssub = 0; ssub < 4; ++ssub) {
#pragma unroll
                        for (int r = 0; r < 4; ++r) {
                            const int s = sbase + ssub * 16 + quad * 4 + r;
                            if (s > qb + l15) sv[ssub][r] = -1e38f;
                        }
                    }
                }
                // --- online softmax per q (=l15), cross-quad via shfl 16/32 ---
                float mx = sv[0][0];
#pragma unroll
                for (int ssub = 0; ssub < 4; ++ssub)
#pragma unroll
                    for (int r = 0; r < 4; ++r) mx = fmaxf(mx, sv[ssub][r]);
                mx = fmaxf(mx, __shfl_xor(mx, 16));
                mx = fmaxf(mx, __shfl_xor(mx, 32));
                const float mold = m_;
                const float mnew = fmaxf(mold, mx);
                const float al = exp2f(mold - mnew);
                float rs = 0.f;
                float p[4][4];
#pragma unroll
                for (int ssub = 0; ssub < 4; ++ssub)
#pragma unroll
                    for (int r = 0; r < 4; ++r) {
                        p[ssub][r] = exp2f(sv[ssub][r] - mnew);
                        rs += p[ssub][r];
                    }
                rs += __shfl_xor(rs, 16);
                rs += __shfl_xor(rs, 32);
                l_ = l_ * al + rs;
                m_ = mnew;
                // --- store P (b64, bank-uniform) ---
#pragma unroll
                for (int ssub = 0; ssub < 4; ++ssub) {
                    bf16x4 pk;
#pragma unroll
                    for (int r = 0; r < 4; ++r) pk[r] = (bf16)p[ssub][r];
                    *(bf16x4*)&Ps[w][l15][ssub * 16 + quad * 4] = pk;
                }
                // --- realign alpha to PV C-layout rows & rescale O ---
                float alr[4];
#pragma unroll
                for (int r = 0; r < 4; ++r) alr[r] = __shfl(al, quad * 4 + r);
#pragma unroll
                for (int nsub = 0; nsub < 4; ++nsub)
#pragma unroll
                    for (int r = 0; r < 4; ++r) accO[nsub][r] *= alr[r];
                // --- O += P V ---
                __builtin_amdgcn_s_setprio(1);
#pragma unroll
                for (int kc2 = 0; kc2 < 2; ++kc2) {
                    bf16x8 Pf = *(const bf16x8*)&Ps[w][l15][kc2 * 32 + quad * 8];
#pragma unroll
                    for (int nsub = 0; nsub < 4; ++nsub) {
                        bf16x8 Vf = *(const bf16x8*)&Vt[nsub * 16 + l15][kc2 * 32 + quad * 8];
                        accO[nsub] =
                            __builtin_amdgcn_mfma_f32_16x16x32_bf16(Pf, Vf, accO[nsub], 0, 0, 0);
                    }
                }
                __builtin_amdgcn_s_setprio(0);
            }
        }
        // --- epilogue: h = x + O / l ---
        {
            const float linv = 1.f / l_;
            float invr[4];
#pragma unroll
            for (int r = 0; r < 4; ++r) invr[r] = __shfl(linv, quad * 4 + r);
#pragma unroll
            for (int r = 0; r < 4; ++r) {
                const size_t row = (size_t)(b * T_SZ + qwave + quad * 4 + r);
                const size_t base = row * D_DIM + (size_t)hh * 64 + l15;
#pragma unroll
                for (int nsub = 0; nsub < 4; ++nsub) {
                    const size_t idx = base + nsub * 16;
                    h[idx] = x[idx] + accO[nsub][r] * invr[r];
                }
            }
        }
    }
}

// ---------------------------------------------------------------- unembed MFMA: out[M,64] = A[M,1024] @ W[64,1024]^T + bun
__global__ __launch_bounds__(256) void unembed_kernel(const bf16* __restrict__ A,
                                                      const bf16* __restrict__ W,
                                                      const float* __restrict__ bun,
                                                      float* __restrict__ out) {
    __shared__ __align__(16) bf16 As[128][64];
    __shared__ __align__(16) bf16 Ws[64][64];
    const int tid = threadIdx.x, lane = tid & 63, w = tid >> 6;
    const int l15 = lane & 15, quad = lane >> 4;
    const size_t rowbase = (size_t)blockIdx.x * 128;
    const int rsub = lane >> 3, schunk = lane & 7, gchunk = schunk ^ rsub;
    const bf16* Ag = A + (rowbase + w * 32 + rsub) * (size_t)D_DIM + gchunk * 8;
    const bf16* Wg = W + (w * 16 + rsub) * (size_t)D_DIM + gchunk * 8;
    bf16* Asl = &As[w * 32][0];
    bf16* Wsl = &Ws[w * 16][0];
    const int swz = l15 & 7;
    f32x4v acc[2][4] = {};
    for (int k0 = 0; k0 < D_DIM; k0 += 64) {
        __syncthreads();
#pragma unroll
        for (int i = 0; i < 4; ++i)
            async16(Ag + k0 + (size_t)(i * 8) * D_DIM, Asl + i * 512);
#pragma unroll
        for (int i = 0; i < 2; ++i)
            async16(Wg + k0 + (size_t)(i * 8) * D_DIM, Wsl + i * 512);
        __syncthreads();
#pragma unroll
        for (int kk = 0; kk < 2; ++kk) {
            const int q = kk * 4 + quad;
            bf16x8 af[2], bv[4];
#pragma unroll
            for (int f = 0; f < 2; ++f) af[f] = *(const bf16x8*)&As[w * 32 + f * 16 + l15][(q ^ swz) * 8];
#pragma unroll
            for (int f = 0; f < 4; ++f) bv[f] = *(const bf16x8*)&Ws[f * 16 + l15][(q ^ swz) * 8];
#pragma unroll
            for (int fm = 0; fm < 2; ++fm)
#pragma unroll
                for (int fn = 0; fn < 4; ++fn)
                    acc[fm][fn] = __builtin_amdgcn_mfma_f32_16x16x32_bf16(af[fm], bv[fn], acc[fm][fn], 0, 0, 0);
        }
    }
#pragma unroll
    for (int fm = 0; fm < 2; ++fm)
#pragma unroll
        for (int r = 0; r < 4; ++r) {
            const size_t row = rowbase + w * 32 + fm * 16 + quad * 4 + r;
#pragma unroll
            for (int fn = 0; fn < 4; ++fn) {
                const int col = fn * 16 + l15;
                out[row * V_DIM + col] = acc[fm][fn][r] + bun[col];
            }
        }
}

// ---------------------------------------------------------------- host
extern "C" void kernel_launch(void* const* d_in, const int* in_sizes, int n_in,
                              void* d_out, int out_size, void* d_ws, size_t ws_size,
                              hipStream_t stream) {
    (void)in_sizes; (void)n_in; (void)out_size;
    const float* toks = (const float*)d_in[0];
    const float* wtok = (const float*)d_in[1];
    const float* wpos = (const float*)d_in[2];
    const float* wqkv = (const float*)d_in[3];
    const float* g1   = (const float*)d_in[4];
    const float* be1  = (const float*)d_in[5];
    const float* w1   = (const float*)d_in[6];
    const float* bm1  = (const float*)d_in[7];
    const float* w2   = (const float*)d_in[8];
    const float* bm2  = (const float*)d_in[9];
    const float* g2   = (const float*)d_in[10];
    const float* be2  = (const float*)d_in[11];
    const float* gf   = (const float*)d_in[12];
    const float* bfp  = (const float*)d_in[13];
    const float* wun  = (const float*)d_in[14];
    const float* bun  = (const float*)d_in[15];
    float* out = (float*)d_out;

    char* ws = (char*)d_ws;
    size_t off = 0;
    auto take = [&](size_t n) { char* p = ws + off; off += (n + 255) & ~(size_t)255; return p; };
    float* xf   = (float*)take((size_t)N_TOK * D_DIM * 4);
    float* hf   = (float*)take((size_t)N_TOK * D_DIM * 4);
    bf16* lnb   = (bf16*)take((size_t)N_TOK * D_DIM * 2);
    bf16* qkvb  = (bf16*)take((size_t)N_TOK * 3 * D_DIM * 2);
    bf16* a1b   = (bf16*)take((size_t)N_TOK * M_DIM * 2);
    bf16* toksb = (bf16*)take((size_t)N_TOK * V_DIM * 2);
    bf16* wtokb = (bf16*)take((size_t)D_DIM * V_DIM * 2);
    bf16* wunb  = (bf16*)take((size_t)V_DIM * D_DIM * 2);
    float* posT = (float*)take((size_t)TMAXP * D_DIM * 4);

    const size_t perL_q = (size_t)3 * D_DIM * D_DIM;   // elems
    const size_t perL_1 = (size_t)M_DIM * D_DIM;
    const size_t perL_2 = (size_t)D_DIM * M_DIM;
    const size_t all_bytes = (size_t)L_NUM * (perL_q + perL_1 + perL_2) * 2 + 4096;
    const bool pre = (ws_size > off) && (ws_size - off >= all_bytes);

    bf16 *wqb, *w1b, *w2b;
    if (pre) {
        wqb = (bf16*)take((size_t)L_NUM * perL_q * 2);
        w1b = (bf16*)take((size_t)L_NUM * perL_1 * 2);
        w2b = (bf16*)take((size_t)L_NUM * perL_2 * 2);
    } else {
        wqb = (bf16*)take(perL_q * 2);
        w1b = (bf16*)take(perL_1 * 2);
        w2b = (bf16*)take(perL_2 * 2);
    }

    convert_kernel<<<(N_TOK * V_DIM) / 1024, 256, 0, stream>>>(toks, toksb, N_TOK * V_DIM);
    convert_kernel<<<(D_DIM * V_DIM) / 1024, 256, 0, stream>>>(wtok, wtokb, D_DIM * V_DIM);
    transpose_pos<<<dim3(TMAXP / 32, D_DIM / 32), 256, 0, stream>>>(wpos, posT);
    gemm_bt<3><<<dim3(D_DIM / 128, N_TOK / 128), 256, 0, stream>>>(
        toksb, wtokb, nullptr, posT, nullptr, xf, nullptr, V_DIM, D_DIM);

    if (pre) {  // hoist all weight converts out of the layer loop (3 launches instead of 24)
        convert_kernel<<<(int)((L_NUM * perL_q) / 1024), 256, 0, stream>>>(
            wqkv, wqb, (int)(L_NUM * perL_q));
        convert_kernel<<<(int)((L_NUM * perL_1) / 1024), 256, 0, stream>>>(
            w1, w1b, (int)(L_NUM * perL_1));
        convert_kernel<<<(int)((L_NUM * perL_2) / 1024), 256, 0, stream>>>(
            w2, w2b, (int)(L_NUM * perL_2));
    }

    for (int l = 0; l < L_NUM; ++l) {
        bf16* wq_l = pre ? wqb + (size_t)l * perL_q : wqb;
        bf16* w1_l = pre ? w1b + (size_t)l * perL_1 : w1b;
        bf16* w2_l = pre ? w2b + (size_t)l * perL_2 : w2b;
        if (!pre)
            convert_kernel<<<(int)(perL_q / 1024), 256, 0, stream>>>(
                wqkv + (size_t)l * perL_q, wq_l, (int)perL_q);
        ln_kernel<<<N_TOK, 256, 0, stream>>>(xf, g1 + l * D_DIM, be1 + l * D_DIM, lnb);
        gemm_bt<0><<<dim3(3 * D_DIM / 128, N_TOK / 128), 256, 0, stream>>>(
            lnb, wq_l, nullptr, nullptr, nullptr, nullptr, qkvb, D_DIM, 3 * D_DIM);
        // causal-paired attention: uniform 34 K-tiles per block, 512 blocks x 8 waves
        attn_kernel<<<dim3(T_SZ / 256, H_NUM, B_SZ), 512, 0, stream>>>(qkvb, xf, hf);
        ln_kernel<<<N_TOK, 256, 0, stream>>>(hf, g2 + l * D_DIM, be2 + l * D_DIM, lnb);
        if (!pre)
            convert_kernel<<<(int)(perL_1 / 1024), 256, 0, stream>>>(
                w1 + (size_t)l * perL_1, w1_l, (int)perL_1);
        // MLP1: 256x256 double-buffered GEMM — grid 16x32 = 512 blocks.
        gemm256_bt<1><<<dim3(M_DIM / 256, N_TOK / 256), 512, 0, stream>>>(
            lnb, w1_l, bm1 + l * M_DIM, nullptr, a1b, D_DIM, M_DIM);
        if (!pre)
            convert_kernel<<<(int)(perL_2 / 1024), 256, 0, stream>>>(
                w2 + (size_t)l * perL_2, w2_l, (int)perL_2);
        gemm_bt<2><<<dim3(D_DIM / 128, N_TOK / 128), 256, 0, stream>>>(
            a1b, w2_l, bm2 + l * D_DIM, xf, hf, xf, nullptr, M_DIM, D_DIM);
    }
    ln_kernel<<<N_TOK, 256, 0, stream>>>(xf, gf, bfp, lnb);
    convert_kernel<<<(V_DIM * D_DIM) / 1024, 256, 0, stream>>>(wun, wunb, V_DIM * D_DIM);
    unembed_kernel<<<N_TOK / 128, 256, 0, stream>>>(lnb, wunb, bun, out);
}